// Round 1
// baseline (1136.809 us; speedup 1.0000x reference)
//
#include <hip/hip_runtime.h>
#include <hip/hip_bf16.h>
#include <math.h>

typedef __bf16 bf16;
typedef __bf16 bf16x4 __attribute__((ext_vector_type(4)));
typedef __bf16 bf16x8 __attribute__((ext_vector_type(8)));
typedef float  floatx4 __attribute__((ext_vector_type(4)));

#define N_TOK 8192   // B*S
#define E_DIM 1024
#define G_DIM 8
#define O_DIM 4096
#define K_BIG 8192   // G*E

__device__ __forceinline__ void gload_lds16(const void* g, void* l) {
    __builtin_amdgcn_global_load_lds(
        (__attribute__((address_space(1))) void*)(g),
        (__attribute__((address_space(3))) void*)(l),
        16, 0, 0);
}

// ---------------------------------------------------------------------------
// 1) gate = X @ WG, top-2, w = sigmoid(gate) for selected else 0.5
//    one wave per token
// ---------------------------------------------------------------------------
__global__ __launch_bounds__(256) void gate_kernel(
    const float* __restrict__ X,   // [N_TOK][E_DIM]
    const float* __restrict__ WG,  // [E_DIM][G_DIM]
    float* __restrict__ Wout)      // [N_TOK][G_DIM]
{
    const int t    = blockIdx.x * 4 + (threadIdx.x >> 6);
    const int lane = threadIdx.x & 63;

    float acc[G_DIM];
#pragma unroll
    for (int g = 0; g < G_DIM; ++g) acc[g] = 0.f;

    const float* xr = X + (long)t * E_DIM;
    for (int e = lane; e < E_DIM; e += 64) {
        const float x = xr[e];
        const float* wg = WG + (long)e * G_DIM;
#pragma unroll
        for (int g = 0; g < G_DIM; ++g) acc[g] += x * wg[g];
    }
#pragma unroll
    for (int g = 0; g < G_DIM; ++g) {
        float v = acc[g];
#pragma unroll
        for (int off = 32; off > 0; off >>= 1) v += __shfl_down(v, off, 64);
        acc[g] = v;  // valid on lane 0
    }
    if (lane == 0) {
        int i1 = 0;
#pragma unroll
        for (int g = 1; g < G_DIM; ++g) if (acc[g] > acc[i1]) i1 = g;
        int i2 = (i1 == 0) ? 1 : 0;
#pragma unroll
        for (int g = 0; g < G_DIM; ++g)
            if (g != i1 && g != i2 && acc[g] > acc[i2]) i2 = g;
#pragma unroll
        for (int g = 0; g < G_DIM; ++g) {
            const float w = (g == i1 || g == i2) ? (1.f / (1.f + expf(-acc[g]))) : 0.5f;
            Wout[(long)t * G_DIM + g] = w;
        }
    }
}

// ---------------------------------------------------------------------------
// 2) A'[t][g*1024+e] = bf16(X[t][e] * w[t][g]);  one block per token
// ---------------------------------------------------------------------------
__global__ __launch_bounds__(256) void build_a(
    const float* __restrict__ X,    // [N_TOK][E_DIM]
    const float* __restrict__ W8,   // [N_TOK][G_DIM]
    bf16* __restrict__ Ap)          // [N_TOK][K_BIG]
{
    const int t   = blockIdx.x;
    const int tid = threadIdx.x;

    float w[G_DIM];
#pragma unroll
    for (int g = 0; g < G_DIM; ++g) w[g] = W8[(long)t * G_DIM + g];

    const float4 xv = *(const float4*)(X + (long)t * E_DIM + tid * 4);
#pragma unroll
    for (int g = 0; g < G_DIM; ++g) {
        bf16x4 o;
        o[0] = (bf16)(xv.x * w[g]);
        o[1] = (bf16)(xv.y * w[g]);
        o[2] = (bf16)(xv.z * w[g]);
        o[3] = (bf16)(xv.w * w[g]);
        *(bf16x4*)(Ap + (long)t * K_BIG + g * E_DIM + tid * 4) = o;
    }
}

// ---------------------------------------------------------------------------
// 3) transpose + fp32->bf16: S[R][C] -> D[C][R]
// ---------------------------------------------------------------------------
__global__ __launch_bounds__(256) void transpose_conv(
    const float* __restrict__ S, bf16* __restrict__ D, int R, int C)
{
    __shared__ float tile[64][65];
    const int r0  = blockIdx.x * 64;
    const int c0  = blockIdx.y * 64;
    const int tid = threadIdx.x;
    const int tr  = tid >> 4;          // 0..15
    const int tc4 = (tid & 15) * 4;    // 0..60

#pragma unroll
    for (int p = 0; p < 4; ++p) {
        const int r = p * 16 + tr;
        const float4 v = *(const float4*)(S + (long)(r0 + r) * C + c0 + tc4);
        tile[r][tc4 + 0] = v.x;
        tile[r][tc4 + 1] = v.y;
        tile[r][tc4 + 2] = v.z;
        tile[r][tc4 + 3] = v.w;
    }
    __syncthreads();
#pragma unroll
    for (int p = 0; p < 4; ++p) {
        const int c = p * 16 + tr;     // source col == dest row
        bf16x4 o;
        o[0] = (bf16)tile[tc4 + 0][c];
        o[1] = (bf16)tile[tc4 + 1][c];
        o[2] = (bf16)tile[tc4 + 2][c];
        o[3] = (bf16)tile[tc4 + 3][c];
        *(bf16x4*)(D + (long)(c0 + c) * R + r0 + tc4) = o;
    }
}

// ---------------------------------------------------------------------------
// 4/5) bf16 GEMM, m97 structure: 128x128 tile, BK=32, global_load_lds(16B),
//      16x16x32 MFMA, 4 waves in 2x2, 4x4 frags/wave.
//      A [M][K] row-major bf16, BT [N][K] row-major bf16.
//      EPI==0: C = bf16(relu(acc)^2)   (for h)
//      EPI==1: C = float(acc)          (final output)
// ---------------------------------------------------------------------------
template <int EPI>
__global__ __launch_bounds__(256, 2) void gemm_kernel(
    const bf16* __restrict__ A, const bf16* __restrict__ BT,
    void* __restrict__ C, int M, int N, int K)
{
    __shared__ bf16 As[128 * 32];
    __shared__ bf16 Bs[128 * 32];

    const int tid  = threadIdx.x;
    const int wave = tid >> 6;
    const int lane = tid & 63;
    const int row0 = blockIdx.x * 128;
    const int col0 = blockIdx.y * 128;

    // staging: instr i covers rows 16i..16i+15; lane -> row 16i + lane/4, k-col 8*(lane%4)
    const int sr = lane >> 2;
    const int sc = (lane & 3) * 8;
    const bf16* agp0 = A  + (long)(row0 + 16 * wave        + sr) * K + sc;
    const bf16* agp1 = A  + (long)(row0 + 16 * (wave + 4)  + sr) * K + sc;
    const bf16* bgp0 = BT + (long)(col0 + 16 * wave        + sr) * K + sc;
    const bf16* bgp1 = BT + (long)(col0 + 16 * (wave + 4)  + sr) * K + sc;
    bf16* asl0 = As + (long)wave * 512;
    bf16* asl1 = As + (long)(wave + 4) * 512;
    bf16* bsl0 = Bs + (long)wave * 512;
    bf16* bsl1 = Bs + (long)(wave + 4) * 512;

    const int mi_base = (wave >> 1) * 64;
    const int ni_base = (wave & 1) * 64;
    const int fr = lane & 15;   // frag row/col
    const int fq = lane >> 4;   // quad

    floatx4 acc[4][4] = {};

    for (int k0 = 0; k0 < K; k0 += 32) {
        __syncthreads();
        gload_lds16(agp0 + k0, (void*)asl0);
        gload_lds16(agp1 + k0, (void*)asl1);
        gload_lds16(bgp0 + k0, (void*)bsl0);
        gload_lds16(bgp1 + k0, (void*)bsl1);
        __syncthreads();

        bf16x8 af[4], bfr[4];
#pragma unroll
        for (int i = 0; i < 4; ++i) {
            af[i]  = *(const bf16x8*)(As + (mi_base + i * 16 + fr) * 32 + fq * 8);
            bfr[i] = *(const bf16x8*)(Bs + (ni_base + i * 16 + fr) * 32 + fq * 8);
        }
#pragma unroll
        for (int i = 0; i < 4; ++i)
#pragma unroll
            for (int j = 0; j < 4; ++j)
                acc[i][j] = __builtin_amdgcn_mfma_f32_16x16x32_bf16(
                    af[i], bfr[j], acc[i][j], 0, 0, 0);
    }

    // epilogue: C[row][col], row = row0+mi_base+i*16+fq*4+r, col = col0+ni_base+j*16+fr
#pragma unroll
    for (int i = 0; i < 4; ++i) {
#pragma unroll
        for (int j = 0; j < 4; ++j) {
#pragma unroll
            for (int r = 0; r < 4; ++r) {
                const long row = row0 + mi_base + i * 16 + fq * 4 + r;
                const long col = col0 + ni_base + j * 16 + fr;
                float v = acc[i][j][r];
                if (EPI == 0) {
                    v = fmaxf(v, 0.f);
                    v = v * v;
                    ((bf16*)C)[row * N + col] = (bf16)v;
                } else {
                    ((float*)C)[row * N + col] = v;
                }
            }
        }
    }
}

// ---------------------------------------------------------------------------
extern "C" void kernel_launch(void* const* d_in, const int* in_sizes, int n_in,
                              void* d_out, int out_size, void* d_ws, size_t ws_size,
                              hipStream_t stream)
{
    const float* X  = (const float*)d_in[0];  // [4,2048,1024]
    const float* WG = (const float*)d_in[1];  // [1024,8]
    const float* Wi = (const float*)d_in[2];  // [8,1024,4096] == [K_BIG][O_DIM]
    const float* dn = (const float*)d_in[3];  // [4096,1024]
    float* out = (float*)d_out;               // [8192][1024] fp32

    char* ws = (char*)d_ws;
    float* Wrow = (float*)ws;                                   // 256 KB
    bf16*  Ap   = (bf16*)(ws + (1l << 20));                     // 128 MB
    bf16*  WiT  = (bf16*)(ws + (1l << 20) + 134217728l);        // 64 MB
    bf16*  dnT  = (bf16*)(ws + (1l << 20) + 134217728l + 67108864l);          // 8 MB
    bf16*  Hh   = (bf16*)(ws + (1l << 20) + 134217728l + 67108864l + 8388608l); // 64 MB

    gate_kernel<<<dim3(N_TOK / 4), dim3(256), 0, stream>>>(X, WG, Wrow);
    build_a<<<dim3(N_TOK), dim3(256), 0, stream>>>(X, Wrow, Ap);
    transpose_conv<<<dim3(K_BIG / 64, O_DIM / 64), dim3(256), 0, stream>>>(Wi, WiT, K_BIG, O_DIM);
    transpose_conv<<<dim3(O_DIM / 64, E_DIM / 64), dim3(256), 0, stream>>>(dn, dnT, O_DIM, E_DIM);
    gemm_kernel<0><<<dim3(N_TOK / 128, O_DIM / 128), dim3(256), 0, stream>>>(
        Ap, WiT, (void*)Hh, N_TOK, O_DIM, K_BIG);
    gemm_kernel<1><<<dim3(N_TOK / 128, E_DIM / 128), dim3(256), 0, stream>>>(
        Hh, dnT, (void*)out, N_TOK, E_DIM, O_DIM);
}

// Round 2
// 1087.587 us; speedup vs baseline: 1.0453x; 1.0453x over previous
//
#include <hip/hip_runtime.h>
#include <hip/hip_bf16.h>
#include <math.h>

typedef __bf16 bf16;
typedef __bf16 bf16x4 __attribute__((ext_vector_type(4)));
typedef __bf16 bf16x8 __attribute__((ext_vector_type(8)));
typedef float  floatx4 __attribute__((ext_vector_type(4)));

#define N_TOK 8192   // B*S
#define E_DIM 1024
#define G_DIM 8
#define O_DIM 4096

__device__ __forceinline__ void gload_lds16(const void* g, void* l) {
    __builtin_amdgcn_global_load_lds(
        (__attribute__((address_space(1))) void*)(g),
        (__attribute__((address_space(3))) void*)(l),
        16, 0, 0);
}

// ---------------------------------------------------------------------------
// 1) gate = X @ WG; top-2; route: per-expert token lists with scale sig-0.5
//    one wave per token
// ---------------------------------------------------------------------------
__global__ __launch_bounds__(256) void gate_kernel(
    const float* __restrict__ X,   // [N_TOK][E_DIM]
    const float* __restrict__ WG,  // [E_DIM][G_DIM]
    int* __restrict__ cnt,         // [G_DIM]
    int* __restrict__ tok,         // [G_DIM][N_TOK]
    float* __restrict__ scl)       // [G_DIM][N_TOK]
{
    const int t    = blockIdx.x * 4 + (threadIdx.x >> 6);
    const int lane = threadIdx.x & 63;

    float acc[G_DIM];
#pragma unroll
    for (int g = 0; g < G_DIM; ++g) acc[g] = 0.f;

    const float* xr = X + (long)t * E_DIM;
    for (int e = lane; e < E_DIM; e += 64) {
        const float x = xr[e];
        const float* wg = WG + (long)e * G_DIM;
#pragma unroll
        for (int g = 0; g < G_DIM; ++g) acc[g] += x * wg[g];
    }
#pragma unroll
    for (int g = 0; g < G_DIM; ++g) {
        float v = acc[g];
#pragma unroll
        for (int off = 32; off > 0; off >>= 1) v += __shfl_down(v, off, 64);
        acc[g] = v;  // valid on lane 0
    }
    if (lane == 0) {
        int i1 = 0;
#pragma unroll
        for (int g = 1; g < G_DIM; ++g) if (acc[g] > acc[i1]) i1 = g;
        int i2 = (i1 == 0) ? 1 : 0;
#pragma unroll
        for (int g = 0; g < G_DIM; ++g)
            if (g != i1 && g != i2 && acc[g] > acc[i2]) i2 = g;
#pragma unroll
        for (int s = 0; s < 2; ++s) {
            const int g = s ? i2 : i1;
            const float w = 1.f / (1.f + expf(-acc[g])) - 0.5f;
            const int p = atomicAdd(&cnt[g], 1);
            tok[g * N_TOK + p] = t;
            scl[g * N_TOK + p] = w;
        }
    }
}

// ---------------------------------------------------------------------------
// 2) X fp32 -> bf16
// ---------------------------------------------------------------------------
__global__ __launch_bounds__(256) void convert_x(
    const float* __restrict__ X, bf16* __restrict__ Xb)
{
    const long i = ((long)blockIdx.x * 256 + threadIdx.x) * 4;
    const float4 v = *(const float4*)(X + i);
    bf16x4 o;
    o[0] = (bf16)v.x; o[1] = (bf16)v.y; o[2] = (bf16)v.z; o[3] = (bf16)v.w;
    *(bf16x4*)(Xb + i) = o;
}

// ---------------------------------------------------------------------------
// 3) transpose + fp32->bf16: S[R][C] -> D[C][R]
// ---------------------------------------------------------------------------
__global__ __launch_bounds__(256) void transpose_conv(
    const float* __restrict__ S, bf16* __restrict__ D, int R, int C)
{
    __shared__ float tile[64][65];
    const int r0  = blockIdx.x * 64;
    const int c0  = blockIdx.y * 64;
    const int tid = threadIdx.x;
    const int tr  = tid >> 4;          // 0..15
    const int tc4 = (tid & 15) * 4;    // 0..60

#pragma unroll
    for (int p = 0; p < 4; ++p) {
        const int r = p * 16 + tr;
        const float4 v = *(const float4*)(S + (long)(r0 + r) * C + c0 + tc4);
        tile[r][tc4 + 0] = v.x;
        tile[r][tc4 + 1] = v.y;
        tile[r][tc4 + 2] = v.z;
        tile[r][tc4 + 3] = v.w;
    }
    __syncthreads();
#pragma unroll
    for (int p = 0; p < 4; ++p) {
        const int c = p * 16 + tr;     // source col == dest row
        bf16x4 o;
        o[0] = (bf16)tile[tc4 + 0][c];
        o[1] = (bf16)tile[tc4 + 1][c];
        o[2] = (bf16)tile[tc4 + 2][c];
        o[3] = (bf16)tile[tc4 + 3][c];
        *(bf16x4*)(D + (long)(c0 + c) * R + r0 + tc4) = o;
    }
}

// ---------------------------------------------------------------------------
// 4) WsumT[o][e] = 0.5 * sum_g WiT[o][g*1024+e]   (bf16)
// ---------------------------------------------------------------------------
__global__ __launch_bounds__(256) void wsum_kernel(
    const bf16* __restrict__ WiT, bf16* __restrict__ WsumT)
{
    const int o  = blockIdx.x;
    const int e4 = threadIdx.x * 4;
    float a0 = 0.f, a1 = 0.f, a2 = 0.f, a3 = 0.f;
#pragma unroll
    for (int g = 0; g < G_DIM; ++g) {
        const bf16x4 v = *(const bf16x4*)(WiT + (long)o * 8192 + g * E_DIM + e4);
        a0 += (float)v[0]; a1 += (float)v[1]; a2 += (float)v[2]; a3 += (float)v[3];
    }
    bf16x4 w;
    w[0] = (bf16)(0.5f * a0); w[1] = (bf16)(0.5f * a1);
    w[2] = (bf16)(0.5f * a2); w[3] = (bf16)(0.5f * a3);
    *(bf16x4*)(WsumT + (long)o * E_DIM + e4) = w;
}

// ---------------------------------------------------------------------------
// 5) generic bf16 GEMM, fp32 out. A [M][lda], BT [N][ldb] row-major bf16.
//    m97 structure: 128x128 tile, BK=32, global_load_lds(16B), 16x16x32 MFMA.
// ---------------------------------------------------------------------------
__global__ __launch_bounds__(256, 2) void gemm_f32(
    const bf16* __restrict__ A, int lda,
    const bf16* __restrict__ BT, int ldb,
    float* __restrict__ C, int ldc, int K)
{
    __shared__ bf16 As[128 * 32];
    __shared__ bf16 Bs[128 * 32];

    const int tid  = threadIdx.x;
    const int wave = tid >> 6;
    const int lane = tid & 63;
    const int row0 = blockIdx.x * 128;
    const int col0 = blockIdx.y * 128;

    const int sr = lane >> 2;
    const int sc = (lane & 3) * 8;
    const bf16* agp0 = A  + (long)(row0 + 16 * wave       + sr) * lda + sc;
    const bf16* agp1 = A  + (long)(row0 + 16 * (wave + 4) + sr) * lda + sc;
    const bf16* bgp0 = BT + (long)(col0 + 16 * wave       + sr) * ldb + sc;
    const bf16* bgp1 = BT + (long)(col0 + 16 * (wave + 4) + sr) * ldb + sc;
    bf16* asl0 = As + (long)wave * 512;
    bf16* asl1 = As + (long)(wave + 4) * 512;
    bf16* bsl0 = Bs + (long)wave * 512;
    bf16* bsl1 = Bs + (long)(wave + 4) * 512;

    const int mi_base = (wave >> 1) * 64;
    const int ni_base = (wave & 1) * 64;
    const int fr = lane & 15;
    const int fq = lane >> 4;

    floatx4 acc[4][4] = {};

    for (int k0 = 0; k0 < K; k0 += 32) {
        __syncthreads();
        gload_lds16(agp0 + k0, (void*)asl0);
        gload_lds16(agp1 + k0, (void*)asl1);
        gload_lds16(bgp0 + k0, (void*)bsl0);
        gload_lds16(bgp1 + k0, (void*)bsl1);
        __syncthreads();

        bf16x8 af[4], bfr[4];
#pragma unroll
        for (int i = 0; i < 4; ++i) {
            af[i]  = *(const bf16x8*)(As + (mi_base + i * 16 + fr) * 32 + fq * 8);
            bfr[i] = *(const bf16x8*)(Bs + (ni_base + i * 16 + fr) * 32 + fq * 8);
        }
#pragma unroll
        for (int i = 0; i < 4; ++i)
#pragma unroll
            for (int j = 0; j < 4; ++j)
                acc[i][j] = __builtin_amdgcn_mfma_f32_16x16x32_bf16(
                    af[i], bfr[j], acc[i][j], 0, 0, 0);
    }

#pragma unroll
    for (int i = 0; i < 4; ++i)
#pragma unroll
        for (int j = 0; j < 4; ++j)
#pragma unroll
            for (int r = 0; r < 4; ++r) {
                const long row = row0 + mi_base + i * 16 + fq * 4 + r;
                const long col = col0 + ni_base + j * 16 + fr;
                C[row * ldc + col] = acc[i][j][r];
            }
}

// ---------------------------------------------------------------------------
// 6) sparse grouped GEMM: for expert g, gathered rows of Xb vs WiT[:,g*1024+..],
//    epilogue atomicAdd scale*acc into ybuf rows tok[].
//    grid: (G_DIM*64, 32)
// ---------------------------------------------------------------------------
__global__ __launch_bounds__(256, 2) void gemm_sparse(
    const bf16* __restrict__ Xb,   // [N_TOK][E_DIM]
    const bf16* __restrict__ WiT,  // [O_DIM][8192]
    const int* __restrict__ cnt,
    const int* __restrict__ tok,
    const float* __restrict__ scl,
    float* __restrict__ ybuf)      // [N_TOK][O_DIM]
{
    const int g  = blockIdx.x >> 6;
    const int mt = blockIdx.x & 63;
    const int m0 = mt * 128;
    const int cg = cnt[g];
    if (m0 >= cg) return;

    const int* tokg = tok + g * N_TOK;
    const float* sclg = scl + g * N_TOK;
    const int cl = cg - 1;

    __shared__ bf16 As[128 * 32];
    __shared__ bf16 Bs[128 * 32];

    const int tid  = threadIdx.x;
    const int wave = tid >> 6;
    const int lane = tid & 63;
    const int col0 = blockIdx.y * 128;

    const int sr = lane >> 2;
    const int sc = (lane & 3) * 8;
    int m_a0 = m0 + 16 * wave       + sr; if (m_a0 > cl) m_a0 = cl;
    int m_a1 = m0 + 16 * (wave + 4) + sr; if (m_a1 > cl) m_a1 = cl;
    const bf16* agp0 = Xb + (long)tokg[m_a0] * E_DIM + sc;
    const bf16* agp1 = Xb + (long)tokg[m_a1] * E_DIM + sc;
    const bf16* bgp0 = WiT + (long)(col0 + 16 * wave       + sr) * 8192 + g * E_DIM + sc;
    const bf16* bgp1 = WiT + (long)(col0 + 16 * (wave + 4) + sr) * 8192 + g * E_DIM + sc;
    bf16* asl0 = As + (long)wave * 512;
    bf16* asl1 = As + (long)(wave + 4) * 512;
    bf16* bsl0 = Bs + (long)wave * 512;
    bf16* bsl1 = Bs + (long)(wave + 4) * 512;

    const int mi_base = (wave >> 1) * 64;
    const int ni_base = (wave & 1) * 64;
    const int fr = lane & 15;
    const int fq = lane >> 4;

    floatx4 acc[4][4] = {};

    for (int k0 = 0; k0 < E_DIM; k0 += 32) {
        __syncthreads();
        gload_lds16(agp0 + k0, (void*)asl0);
        gload_lds16(agp1 + k0, (void*)asl1);
        gload_lds16(bgp0 + k0, (void*)bsl0);
        gload_lds16(bgp1 + k0, (void*)bsl1);
        __syncthreads();

        bf16x8 af[4], bfr[4];
#pragma unroll
        for (int i = 0; i < 4; ++i) {
            af[i]  = *(const bf16x8*)(As + (mi_base + i * 16 + fr) * 32 + fq * 8);
            bfr[i] = *(const bf16x8*)(Bs + (ni_base + i * 16 + fr) * 32 + fq * 8);
        }
#pragma unroll
        for (int i = 0; i < 4; ++i)
#pragma unroll
            for (int j = 0; j < 4; ++j)
                acc[i][j] = __builtin_amdgcn_mfma_f32_16x16x32_bf16(
                    af[i], bfr[j], acc[i][j], 0, 0, 0);
    }

#pragma unroll
    for (int i = 0; i < 4; ++i) {
        int  trow[4]; float srow[4]; bool vrow[4];
#pragma unroll
        for (int r = 0; r < 4; ++r) {
            const int gm = m0 + mi_base + i * 16 + fq * 4 + r;
            vrow[r] = (gm < cg);
            const int gmc = vrow[r] ? gm : cl;
            trow[r] = tokg[gmc];
            srow[r] = sclg[gmc];
        }
#pragma unroll
        for (int j = 0; j < 4; ++j)
#pragma unroll
            for (int r = 0; r < 4; ++r)
                if (vrow[r]) {
                    const long col = col0 + ni_base + j * 16 + fr;
                    atomicAdd(&ybuf[(long)trow[r] * O_DIM + col],
                              srow[r] * acc[i][j][r]);
                }
    }
}

// ---------------------------------------------------------------------------
// 7) h = bf16(relu(y)^2)
// ---------------------------------------------------------------------------
__global__ __launch_bounds__(256) void relu2_kernel(
    const float* __restrict__ Y, bf16* __restrict__ H)
{
    const long i = ((long)blockIdx.x * 256 + threadIdx.x) * 4;
    const float4 v = *(const float4*)(Y + i);
    bf16x4 o;
    float a;
    a = fmaxf(v.x, 0.f); o[0] = (bf16)(a * a);
    a = fmaxf(v.y, 0.f); o[1] = (bf16)(a * a);
    a = fmaxf(v.z, 0.f); o[2] = (bf16)(a * a);
    a = fmaxf(v.w, 0.f); o[3] = (bf16)(a * a);
    *(bf16x4*)(H + i) = o;
}

// ---------------------------------------------------------------------------
extern "C" void kernel_launch(void* const* d_in, const int* in_sizes, int n_in,
                              void* d_out, int out_size, void* d_ws, size_t ws_size,
                              hipStream_t stream)
{
    const float* X  = (const float*)d_in[0];  // [4,2048,1024]
    const float* WG = (const float*)d_in[1];  // [1024,8]
    const float* Wi = (const float*)d_in[2];  // [8,1024,4096] == [8192][4096]
    const float* dn = (const float*)d_in[3];  // [4096,1024]
    float* out = (float*)d_out;               // [8192][1024] fp32

    char* ws = (char*)d_ws;
    const long MB = 1l << 20;
    int*   cnt   = (int*)ws;                        // 256 B (zeroed)
    int*   tok   = (int*)(ws + 16 * 1024);          // 256 KB
    float* scl   = (float*)(ws + 304 * 1024);       // 256 KB
    bf16*  Xb    = (bf16*)(ws + 1 * MB);            // 16 MB
    bf16*  WsumT = (bf16*)(ws + 17 * MB);           // 8 MB
    bf16*  dnT   = (bf16*)(ws + 25 * MB);           // 8 MB
    bf16*  WiT   = (bf16*)(ws + 33 * MB);           // 64 MB
    bf16*  Hh    = (bf16*)(ws + 33 * MB);           // 64 MB (aliases WiT; WiT dead)
    float* ybuf  = (float*)(ws + 97 * MB);          // 128 MB

    hipMemsetAsync(cnt, 0, 256, stream);
    gate_kernel<<<dim3(N_TOK / 4), dim3(256), 0, stream>>>(X, WG, cnt, tok, scl);
    convert_x<<<dim3(N_TOK * E_DIM / 1024), dim3(256), 0, stream>>>(X, Xb);
    transpose_conv<<<dim3(8192 / 64, O_DIM / 64), dim3(256), 0, stream>>>(Wi, WiT, 8192, O_DIM);
    transpose_conv<<<dim3(O_DIM / 64, E_DIM / 64), dim3(256), 0, stream>>>(dn, dnT, O_DIM, E_DIM);
    wsum_kernel<<<dim3(O_DIM), dim3(256), 0, stream>>>(WiT, WsumT);
    // y_base = Xb @ WsumT^T  -> ybuf
    gemm_f32<<<dim3(N_TOK / 128, O_DIM / 128), dim3(256), 0, stream>>>(
        Xb, E_DIM, WsumT, E_DIM, ybuf, O_DIM, E_DIM);
    // y += scale * gathered-X @ Wi[g]
    gemm_sparse<<<dim3(G_DIM * 64, O_DIM / 128), dim3(256), 0, stream>>>(
        Xb, WiT, cnt, tok, scl, ybuf);
    relu2_kernel<<<dim3(N_TOK * O_DIM / 1024), dim3(256), 0, stream>>>(ybuf, Hh);
    // out = Hh @ dnT^T
    gemm_f32<<<dim3(N_TOK / 128, E_DIM / 128), dim3(256), 0, stream>>>(
        Hh, O_DIM, dnT, O_DIM, out, E_DIM, O_DIM);
}

// Round 3
// 1039.152 us; speedup vs baseline: 1.0940x; 1.0466x over previous
//
#include <hip/hip_runtime.h>
#include <hip/hip_bf16.h>
#include <math.h>

typedef __bf16 bf16;
typedef __bf16 bf16x4 __attribute__((ext_vector_type(4)));
typedef __bf16 bf16x8 __attribute__((ext_vector_type(8)));
typedef float  floatx4 __attribute__((ext_vector_type(4)));

#define N_TOK 8192   // B*S
#define E_DIM 1024
#define G_DIM 8
#define O_DIM 4096

__device__ __forceinline__ void gload_lds16(const void* g, void* l) {
    __builtin_amdgcn_global_load_lds(
        (__attribute__((address_space(1))) void*)(g),
        (__attribute__((address_space(3))) void*)(l),
        16, 0, 0);
}

// ---------------------------------------------------------------------------
// 1) gate = X @ WG; top-2; per-expert token lists with scale (sigmoid-0.5);
//    pos[t*2+s] = (g<<16)|p records the token's two slots.
// ---------------------------------------------------------------------------
__global__ __launch_bounds__(256) void gate_kernel(
    const float* __restrict__ X,   // [N_TOK][E_DIM]
    const float* __restrict__ WG,  // [E_DIM][G_DIM]
    int* __restrict__ cnt,         // [G_DIM]
    int* __restrict__ tok,         // [G_DIM][N_TOK]
    float* __restrict__ scl,       // [G_DIM][N_TOK]
    int* __restrict__ pos)         // [N_TOK][2]
{
    const int t    = blockIdx.x * 4 + (threadIdx.x >> 6);
    const int lane = threadIdx.x & 63;

    float acc[G_DIM];
#pragma unroll
    for (int g = 0; g < G_DIM; ++g) acc[g] = 0.f;

    const float* xr = X + (long)t * E_DIM;
    for (int e = lane; e < E_DIM; e += 64) {
        const float x = xr[e];
        const float* wg = WG + (long)e * G_DIM;
#pragma unroll
        for (int g = 0; g < G_DIM; ++g) acc[g] += x * wg[g];
    }
#pragma unroll
    for (int g = 0; g < G_DIM; ++g) {
        float v = acc[g];
#pragma unroll
        for (int off = 32; off > 0; off >>= 1) v += __shfl_down(v, off, 64);
        acc[g] = v;  // valid on lane 0
    }
    if (lane == 0) {
        int i1 = 0;
#pragma unroll
        for (int g = 1; g < G_DIM; ++g) if (acc[g] > acc[i1]) i1 = g;
        int i2 = (i1 == 0) ? 1 : 0;
#pragma unroll
        for (int g = 0; g < G_DIM; ++g)
            if (g != i1 && g != i2 && acc[g] > acc[i2]) i2 = g;
#pragma unroll
        for (int s = 0; s < 2; ++s) {
            const int g = s ? i2 : i1;
            const float w = 1.f / (1.f + expf(-acc[g])) - 0.5f;
            const int p = atomicAdd(&cnt[g], 1);
            tok[g * N_TOK + p] = t;
            scl[g * N_TOK + p] = w;
            pos[t * 2 + s] = (g << 16) | p;
        }
    }
}

// ---------------------------------------------------------------------------
// 1b) exclusive prefix over 8 counts
// ---------------------------------------------------------------------------
__global__ void prefix_kernel(const int* __restrict__ cnt, int* __restrict__ off)
{
    if (threadIdx.x == 0) {
        int a = 0;
#pragma unroll
        for (int g = 0; g < G_DIM; ++g) { off[g] = a; a += cnt[g]; }
    }
}

// ---------------------------------------------------------------------------
// 2) X fp32 -> bf16
// ---------------------------------------------------------------------------
__global__ __launch_bounds__(256) void convert_x(
    const float* __restrict__ X, bf16* __restrict__ Xb)
{
    const long i = ((long)blockIdx.x * 256 + threadIdx.x) * 4;
    const float4 v = *(const float4*)(X + i);
    bf16x4 o;
    o[0] = (bf16)v.x; o[1] = (bf16)v.y; o[2] = (bf16)v.z; o[3] = (bf16)v.w;
    *(bf16x4*)(Xb + i) = o;
}

// ---------------------------------------------------------------------------
// 3) transpose + fp32->bf16: S[R][C] -> D[C][R]
// ---------------------------------------------------------------------------
__global__ __launch_bounds__(256) void transpose_conv(
    const float* __restrict__ S, bf16* __restrict__ D, int R, int C)
{
    __shared__ float tile[64][65];
    const int r0  = blockIdx.x * 64;
    const int c0  = blockIdx.y * 64;
    const int tid = threadIdx.x;
    const int tr  = tid >> 4;          // 0..15
    const int tc4 = (tid & 15) * 4;    // 0..60

#pragma unroll
    for (int p = 0; p < 4; ++p) {
        const int r = p * 16 + tr;
        const float4 v = *(const float4*)(S + (long)(r0 + r) * C + c0 + tc4);
        tile[r][tc4 + 0] = v.x;
        tile[r][tc4 + 1] = v.y;
        tile[r][tc4 + 2] = v.z;
        tile[r][tc4 + 3] = v.w;
    }
    __syncthreads();
#pragma unroll
    for (int p = 0; p < 4; ++p) {
        const int c = p * 16 + tr;     // source col == dest row
        bf16x4 o;
        o[0] = (bf16)tile[tc4 + 0][c];
        o[1] = (bf16)tile[tc4 + 1][c];
        o[2] = (bf16)tile[tc4 + 2][c];
        o[3] = (bf16)tile[tc4 + 3][c];
        *(bf16x4*)(D + (long)(c0 + c) * R + r0 + tc4) = o;
    }
}

// ---------------------------------------------------------------------------
// 4) WsumT[o][e] = 0.5 * sum_g WiT[o][g*1024+e]   (bf16)
// ---------------------------------------------------------------------------
__global__ __launch_bounds__(256) void wsum_kernel(
    const bf16* __restrict__ WiT, bf16* __restrict__ WsumT)
{
    const int o  = blockIdx.x;
    const int e4 = threadIdx.x * 4;
    float a0 = 0.f, a1 = 0.f, a2 = 0.f, a3 = 0.f;
#pragma unroll
    for (int g = 0; g < G_DIM; ++g) {
        const bf16x4 v = *(const bf16x4*)(WiT + (long)o * 8192 + g * E_DIM + e4);
        a0 += (float)v[0]; a1 += (float)v[1]; a2 += (float)v[2]; a3 += (float)v[3];
    }
    bf16x4 w;
    w[0] = (bf16)(0.5f * a0); w[1] = (bf16)(0.5f * a1);
    w[2] = (bf16)(0.5f * a2); w[3] = (bf16)(0.5f * a3);
    *(bf16x4*)(WsumT + (long)o * E_DIM + e4) = w;
}

// ---------------------------------------------------------------------------
// 5) generic bf16 GEMM. A [M][lda], BT [N][ldb] row-major bf16.
//    OUT: float or bf16 store of acc.
// ---------------------------------------------------------------------------
template <typename OUT>
__global__ __launch_bounds__(256, 4) void gemm_mt(
    const bf16* __restrict__ A, int lda,
    const bf16* __restrict__ BT, int ldb,
    OUT* __restrict__ C, int ldc, int K)
{
    __shared__ bf16 As[128 * 32];
    __shared__ bf16 Bs[128 * 32];

    const int tid  = threadIdx.x;
    const int wave = tid >> 6;
    const int lane = tid & 63;
    const int row0 = blockIdx.x * 128;
    const int col0 = blockIdx.y * 128;

    const int sr = lane >> 2;
    const int sc = (lane & 3) * 8;
    const bf16* agp0 = A  + (long)(row0 + 16 * wave       + sr) * lda + sc;
    const bf16* agp1 = A  + (long)(row0 + 16 * (wave + 4) + sr) * lda + sc;
    const bf16* bgp0 = BT + (long)(col0 + 16 * wave       + sr) * ldb + sc;
    const bf16* bgp1 = BT + (long)(col0 + 16 * (wave + 4) + sr) * ldb + sc;
    bf16* asl0 = As + (long)wave * 512;
    bf16* asl1 = As + (long)(wave + 4) * 512;
    bf16* bsl0 = Bs + (long)wave * 512;
    bf16* bsl1 = Bs + (long)(wave + 4) * 512;

    const int mi_base = (wave >> 1) * 64;
    const int ni_base = (wave & 1) * 64;
    const int fr = lane & 15;
    const int fq = lane >> 4;

    floatx4 acc[4][4] = {};

    for (int k0 = 0; k0 < K; k0 += 32) {
        __syncthreads();
        gload_lds16(agp0 + k0, (void*)asl0);
        gload_lds16(agp1 + k0, (void*)asl1);
        gload_lds16(bgp0 + k0, (void*)bsl0);
        gload_lds16(bgp1 + k0, (void*)bsl1);
        __syncthreads();

        bf16x8 af[4], bfr[4];
#pragma unroll
        for (int i = 0; i < 4; ++i) {
            af[i]  = *(const bf16x8*)(As + (mi_base + i * 16 + fr) * 32 + fq * 8);
            bfr[i] = *(const bf16x8*)(Bs + (ni_base + i * 16 + fr) * 32 + fq * 8);
        }
#pragma unroll
        for (int i = 0; i < 4; ++i)
#pragma unroll
            for (int j = 0; j < 4; ++j)
                acc[i][j] = __builtin_amdgcn_mfma_f32_16x16x32_bf16(
                    af[i], bfr[j], acc[i][j], 0, 0, 0);
    }

#pragma unroll
    for (int i = 0; i < 4; ++i)
#pragma unroll
        for (int j = 0; j < 4; ++j)
#pragma unroll
            for (int r = 0; r < 4; ++r) {
                const long row = row0 + mi_base + i * 16 + fq * 4 + r;
                const long col = col0 + ni_base + j * 16 + fr;
                C[row * ldc + col] = (OUT)acc[i][j][r];
            }
}

// ---------------------------------------------------------------------------
// 6) sparse grouped GEMM: expert g, gathered rows of Xb vs WiT[:,g*1024+..].
//    Epilogue: plain stores of scale*acc into compact slot buffer
//    ysp[off[g]+m][col] (bf16). grid: (G_DIM*64, 32)
// ---------------------------------------------------------------------------
__global__ __launch_bounds__(256, 4) void gemm_sparse(
    const bf16* __restrict__ Xb,   // [N_TOK][E_DIM]
    const bf16* __restrict__ WiT,  // [O_DIM][8192]
    const int* __restrict__ cnt,
    const int* __restrict__ off,
    const int* __restrict__ tok,
    const float* __restrict__ scl,
    bf16* __restrict__ ysp)        // [2*N_TOK][O_DIM]
{
    const int g  = blockIdx.x >> 6;
    const int mt = blockIdx.x & 63;
    const int m0 = mt * 128;
    const int cg = cnt[g];
    if (m0 >= cg) return;
    const int offg = off[g];

    const int* tokg = tok + g * N_TOK;
    const float* sclg = scl + g * N_TOK;
    const int cl = cg - 1;

    __shared__ bf16 As[128 * 32];
    __shared__ bf16 Bs[128 * 32];

    const int tid  = threadIdx.x;
    const int wave = tid >> 6;
    const int lane = tid & 63;
    const int col0 = blockIdx.y * 128;

    const int sr = lane >> 2;
    const int sc = (lane & 3) * 8;
    int m_a0 = m0 + 16 * wave       + sr; if (m_a0 > cl) m_a0 = cl;
    int m_a1 = m0 + 16 * (wave + 4) + sr; if (m_a1 > cl) m_a1 = cl;
    const bf16* agp0 = Xb + (long)tokg[m_a0] * E_DIM + sc;
    const bf16* agp1 = Xb + (long)tokg[m_a1] * E_DIM + sc;
    const bf16* bgp0 = WiT + (long)(col0 + 16 * wave       + sr) * 8192 + g * E_DIM + sc;
    const bf16* bgp1 = WiT + (long)(col0 + 16 * (wave + 4) + sr) * 8192 + g * E_DIM + sc;
    bf16* asl0 = As + (long)wave * 512;
    bf16* asl1 = As + (long)(wave + 4) * 512;
    bf16* bsl0 = Bs + (long)wave * 512;
    bf16* bsl1 = Bs + (long)(wave + 4) * 512;

    const int mi_base = (wave >> 1) * 64;
    const int ni_base = (wave & 1) * 64;
    const int fr = lane & 15;
    const int fq = lane >> 4;

    floatx4 acc[4][4] = {};

    for (int k0 = 0; k0 < E_DIM; k0 += 32) {
        __syncthreads();
        gload_lds16(agp0 + k0, (void*)asl0);
        gload_lds16(agp1 + k0, (void*)asl1);
        gload_lds16(bgp0 + k0, (void*)bsl0);
        gload_lds16(bgp1 + k0, (void*)bsl1);
        __syncthreads();

        bf16x8 af[4], bfr[4];
#pragma unroll
        for (int i = 0; i < 4; ++i) {
            af[i]  = *(const bf16x8*)(As + (mi_base + i * 16 + fr) * 32 + fq * 8);
            bfr[i] = *(const bf16x8*)(Bs + (ni_base + i * 16 + fr) * 32 + fq * 8);
        }
#pragma unroll
        for (int i = 0; i < 4; ++i)
#pragma unroll
            for (int j = 0; j < 4; ++j)
                acc[i][j] = __builtin_amdgcn_mfma_f32_16x16x32_bf16(
                    af[i], bfr[j], acc[i][j], 0, 0, 0);
    }

#pragma unroll
    for (int i = 0; i < 4; ++i) {
        float srow[4]; bool vrow[4]; int grow[4];
#pragma unroll
        for (int r = 0; r < 4; ++r) {
            const int gm = m0 + mi_base + i * 16 + fq * 4 + r;
            vrow[r] = (gm < cg);
            srow[r] = sclg[vrow[r] ? gm : cl];
            grow[r] = offg + gm;
        }
#pragma unroll
        for (int j = 0; j < 4; ++j)
#pragma unroll
            for (int r = 0; r < 4; ++r)
                if (vrow[r]) {
                    const long col = col0 + ni_base + j * 16 + fr;
                    ysp[(long)grow[r] * O_DIM + col] = (bf16)(srow[r] * acc[i][j][r]);
                }
    }
}

// ---------------------------------------------------------------------------
// 7) h = bf16(relu(ybase + ysp[slot0] + ysp[slot1])^2); one block per token
// ---------------------------------------------------------------------------
__global__ __launch_bounds__(256) void relu2_gather(
    const bf16* __restrict__ Yb,   // [N_TOK][O_DIM]
    const bf16* __restrict__ ysp,  // [2*N_TOK][O_DIM]
    const int* __restrict__ pos,   // [N_TOK][2]
    const int* __restrict__ off,   // [G_DIM]
    bf16* __restrict__ H)          // [N_TOK][O_DIM]
{
    const int t  = blockIdx.x;
    const int p0 = pos[t * 2];
    const int p1 = pos[t * 2 + 1];
    const long r0 = off[p0 >> 16] + (p0 & 0xffff);
    const long r1 = off[p1 >> 16] + (p1 & 0xffff);
    const int c = threadIdx.x * 16;

    const bf16* yb = Yb + (long)t * O_DIM + c;
    const bf16* s0 = ysp + r0 * O_DIM + c;
    const bf16* s1 = ysp + r1 * O_DIM + c;
    bf16* hp = H + (long)t * O_DIM + c;

#pragma unroll
    for (int h = 0; h < 2; ++h) {
        const bf16x8 a = *(const bf16x8*)(yb + h * 8);
        const bf16x8 b = *(const bf16x8*)(s0 + h * 8);
        const bf16x8 d = *(const bf16x8*)(s1 + h * 8);
        bf16x8 o;
#pragma unroll
        for (int k = 0; k < 8; ++k) {
            float v = (float)a[k] + (float)b[k] + (float)d[k];
            v = fmaxf(v, 0.f);
            o[k] = (bf16)(v * v);
        }
        *(bf16x8*)(hp + h * 8) = o;
    }
}

// ---------------------------------------------------------------------------
extern "C" void kernel_launch(void* const* d_in, const int* in_sizes, int n_in,
                              void* d_out, int out_size, void* d_ws, size_t ws_size,
                              hipStream_t stream)
{
    const float* X  = (const float*)d_in[0];  // [4,2048,1024]
    const float* WG = (const float*)d_in[1];  // [1024,8]
    const float* Wi = (const float*)d_in[2];  // [8,1024,4096] == [8192][4096]
    const float* dn = (const float*)d_in[3];  // [4096,1024]
    float* out = (float*)d_out;               // [8192][1024] fp32

    char* ws = (char*)d_ws;
    const long MB = 1l << 20;
    int*   cnt   = (int*)ws;                        // 32 B (zeroed)
    int*   off   = (int*)(ws + 1024);               // 32 B
    int*   pos   = (int*)(ws + 2048);               // 64 KB
    int*   tok   = (int*)(ws + 128 * 1024);         // 256 KB
    float* scl   = (float*)(ws + 448 * 1024);       // 256 KB
    bf16*  Xb    = (bf16*)(ws + 1 * MB);            // 16 MB
    bf16*  WsumT = (bf16*)(ws + 17 * MB);           // 8 MB
    bf16*  dnT   = (bf16*)(ws + 25 * MB);           // 8 MB
    bf16*  WiT   = (bf16*)(ws + 33 * MB);           // 64 MB
    bf16*  Hh    = (bf16*)(ws + 33 * MB);           // 64 MB (aliases WiT; dead by then)
    bf16*  Yb    = (bf16*)(ws + 97 * MB);           // 64 MB
    bf16*  ysp   = (bf16*)(ws + 161 * MB);          // 128 MB  -> total 289 MB

    hipMemsetAsync(cnt, 0, 64, stream);
    gate_kernel<<<dim3(N_TOK / 4), dim3(256), 0, stream>>>(X, WG, cnt, tok, scl, pos);
    prefix_kernel<<<dim3(1), dim3(64), 0, stream>>>(cnt, off);
    convert_x<<<dim3(N_TOK * E_DIM / 1024), dim3(256), 0, stream>>>(X, Xb);
    transpose_conv<<<dim3(8192 / 64, O_DIM / 64), dim3(256), 0, stream>>>(Wi, WiT, 8192, O_DIM);
    transpose_conv<<<dim3(O_DIM / 64, E_DIM / 64), dim3(256), 0, stream>>>(dn, dnT, O_DIM, E_DIM);
    wsum_kernel<<<dim3(O_DIM), dim3(256), 0, stream>>>(WiT, WsumT);
    // y_base = Xb @ WsumT^T  (bf16 out)
    gemm_mt<bf16><<<dim3(N_TOK / 128, O_DIM / 128), dim3(256), 0, stream>>>(
        Xb, E_DIM, WsumT, E_DIM, Yb, O_DIM, E_DIM);
    // slot partials: scale * gathered-X @ Wi[g]
    gemm_sparse<<<dim3(G_DIM * 64, O_DIM / 128), dim3(256), 0, stream>>>(
        Xb, WiT, cnt, off, tok, scl, ysp);
    relu2_gather<<<dim3(N_TOK), dim3(256), 0, stream>>>(Yb, ysp, pos, off, Hh);
    // out = Hh @ dnT^T  (fp32 out)
    gemm_mt<float><<<dim3(N_TOK / 128, E_DIM / 128), dim3(256), 0, stream>>>(
        Hh, O_DIM, dnT, O_DIM, out, E_DIM, O_DIM);
}

// Round 4
// 909.339 us; speedup vs baseline: 1.2501x; 1.1428x over previous
//
#include <hip/hip_runtime.h>
#include <hip/hip_bf16.h>
#include <math.h>

typedef __bf16 bf16;
typedef __bf16 bf16x4 __attribute__((ext_vector_type(4)));
typedef __bf16 bf16x8 __attribute__((ext_vector_type(8)));
typedef float  floatx4 __attribute__((ext_vector_type(4)));

#define N_TOK 8192   // B*S
#define E_DIM 1024
#define G_DIM 8
#define O_DIM 4096
#define EPI_LD 132   // padded leading dim of epilogue LDS tile (bf16)

__device__ __forceinline__ void gload_lds16(const void* g, void* l) {
    __builtin_amdgcn_global_load_lds(
        (__attribute__((address_space(1))) void*)(g),
        (__attribute__((address_space(3))) void*)(l),
        16, 0, 0);
}

// ---------------------------------------------------------------------------
// 1) gate = X @ WG; top-2; per-expert token lists with scale (sigmoid-0.5);
//    pos[t*2+s] = (g<<16)|p records the token's two slots.
// ---------------------------------------------------------------------------
__global__ __launch_bounds__(256) void gate_kernel(
    const float* __restrict__ X,   // [N_TOK][E_DIM]
    const float* __restrict__ WG,  // [E_DIM][G_DIM]
    int* __restrict__ cnt,         // [G_DIM]
    int* __restrict__ tok,         // [G_DIM][N_TOK]
    float* __restrict__ scl,       // [G_DIM][N_TOK]
    int* __restrict__ pos)         // [N_TOK][2]
{
    const int t    = blockIdx.x * 4 + (threadIdx.x >> 6);
    const int lane = threadIdx.x & 63;

    float acc[G_DIM];
#pragma unroll
    for (int g = 0; g < G_DIM; ++g) acc[g] = 0.f;

    const float* xr = X + (long)t * E_DIM;
    for (int e = lane; e < E_DIM; e += 64) {
        const float x = xr[e];
        const float* wg = WG + (long)e * G_DIM;
#pragma unroll
        for (int g = 0; g < G_DIM; ++g) acc[g] += x * wg[g];
    }
#pragma unroll
    for (int g = 0; g < G_DIM; ++g) {
        float v = acc[g];
#pragma unroll
        for (int off = 32; off > 0; off >>= 1) v += __shfl_down(v, off, 64);
        acc[g] = v;  // valid on lane 0
    }
    if (lane == 0) {
        int i1 = 0;
#pragma unroll
        for (int g = 1; g < G_DIM; ++g) if (acc[g] > acc[i1]) i1 = g;
        int i2 = (i1 == 0) ? 1 : 0;
#pragma unroll
        for (int g = 0; g < G_DIM; ++g)
            if (g != i1 && g != i2 && acc[g] > acc[i2]) i2 = g;
#pragma unroll
        for (int s = 0; s < 2; ++s) {
            const int g = s ? i2 : i1;
            const float w = 1.f / (1.f + expf(-acc[g])) - 0.5f;
            const int p = atomicAdd(&cnt[g], 1);
            tok[g * N_TOK + p] = t;
            scl[g * N_TOK + p] = w;
            pos[t * 2 + s] = (g << 16) | p;
        }
    }
}

// ---------------------------------------------------------------------------
// 1b) prefix sums: off = exclusive prefix of cnt; offp = exclusive prefix of
//     cnt padded up to multiples of 128 (9 entries, offp[8] = padded total)
// ---------------------------------------------------------------------------
__global__ void prefix_kernel(const int* __restrict__ cnt,
                              int* __restrict__ off, int* __restrict__ offp)
{
    if (threadIdx.x == 0) {
        int a = 0, b = 0;
#pragma unroll
        for (int g = 0; g < G_DIM; ++g) {
            off[g]  = a;  a += cnt[g];
            offp[g] = b;  b += (cnt[g] + 127) & ~127;
        }
        offp[G_DIM] = b;
    }
}

// ---------------------------------------------------------------------------
// 2) X fp32 -> bf16
// ---------------------------------------------------------------------------
__global__ __launch_bounds__(256) void convert_x(
    const float* __restrict__ X, bf16* __restrict__ Xb)
{
    const long i = ((long)blockIdx.x * 256 + threadIdx.x) * 4;
    const float4 v = *(const float4*)(X + i);
    bf16x4 o;
    o[0] = (bf16)v.x; o[1] = (bf16)v.y; o[2] = (bf16)v.z; o[3] = (bf16)v.w;
    *(bf16x4*)(Xb + i) = o;
}

// ---------------------------------------------------------------------------
// 3) transpose + fp32->bf16: S[R][C] -> D[C][R]
// ---------------------------------------------------------------------------
__global__ __launch_bounds__(256) void transpose_conv(
    const float* __restrict__ S, bf16* __restrict__ D, int R, int C)
{
    __shared__ float tile[64][65];
    const int r0  = blockIdx.x * 64;
    const int c0  = blockIdx.y * 64;
    const int tid = threadIdx.x;
    const int tr  = tid >> 4;          // 0..15
    const int tc4 = (tid & 15) * 4;    // 0..60

#pragma unroll
    for (int p = 0; p < 4; ++p) {
        const int r = p * 16 + tr;
        const float4 v = *(const float4*)(S + (long)(r0 + r) * C + c0 + tc4);
        tile[r][tc4 + 0] = v.x;
        tile[r][tc4 + 1] = v.y;
        tile[r][tc4 + 2] = v.z;
        tile[r][tc4 + 3] = v.w;
    }
    __syncthreads();
#pragma unroll
    for (int p = 0; p < 4; ++p) {
        const int c = p * 16 + tr;     // source col == dest row
        bf16x4 o;
        o[0] = (bf16)tile[tc4 + 0][c];
        o[1] = (bf16)tile[tc4 + 1][c];
        o[2] = (bf16)tile[tc4 + 2][c];
        o[3] = (bf16)tile[tc4 + 3][c];
        *(bf16x4*)(D + (long)(c0 + c) * R + r0 + tc4) = o;
    }
}

// ---------------------------------------------------------------------------
// 4) WsumT[o][e] = 0.5 * sum_g WiT[o][g*1024+e]   (bf16)
// ---------------------------------------------------------------------------
__global__ __launch_bounds__(256) void wsum_kernel(
    const bf16* __restrict__ WiT, bf16* __restrict__ WsumT)
{
    const int o  = blockIdx.x;
    const int e4 = threadIdx.x * 4;
    float a0 = 0.f, a1 = 0.f, a2 = 0.f, a3 = 0.f;
#pragma unroll
    for (int g = 0; g < G_DIM; ++g) {
        const bf16x4 v = *(const bf16x4*)(WiT + (long)o * 8192 + g * E_DIM + e4);
        a0 += (float)v[0]; a1 += (float)v[1]; a2 += (float)v[2]; a3 += (float)v[3];
    }
    bf16x4 w;
    w[0] = (bf16)(0.5f * a0); w[1] = (bf16)(0.5f * a1);
    w[2] = (bf16)(0.5f * a2); w[3] = (bf16)(0.5f * a3);
    *(bf16x4*)(WsumT + (long)o * E_DIM + e4) = w;
}

// ---------------------------------------------------------------------------
// 5) gather rows of Xb into expert-sorted, 128-padded Xs. One block per slot.
// ---------------------------------------------------------------------------
__global__ __launch_bounds__(128) void gather_rows(
    const bf16* __restrict__ Xb, const int* __restrict__ cnt,
    const int* __restrict__ offp, const int* __restrict__ tok,
    bf16* __restrict__ Xs)
{
    const int slot = blockIdx.x;
    if (slot >= offp[G_DIM]) return;
    int g = 0;
    while (slot >= offp[g + 1]) ++g;
    const int p = slot - offp[g];
    bf16* dst = Xs + (long)slot * E_DIM + threadIdx.x * 8;
    if (p < cnt[g]) {
        const bf16* src = Xb + (long)tok[g * N_TOK + p] * E_DIM + threadIdx.x * 8;
        *(bf16x8*)dst = *(const bf16x8*)src;
    } else {
        bf16x8 z = {};
        *(bf16x8*)dst = z;
    }
}

// ---------------------------------------------------------------------------
// 6) generic dense bf16 GEMM, 1-D grid with XCD-aware decode.
//    A [M][lda], BT [N][ldb] row-major bf16. 128x128 tile, BK=32.
//    VEC: bf16 out via LDS-staged vectorized epilogue. else fp32 scalar.
//    grid.x = 64 (m-tiles) * NCT (col-tiles); NCT multiple of 8.
// ---------------------------------------------------------------------------
template <typename OUT, bool VEC>
__global__ __launch_bounds__(256, 4) void gemm_mt(
    const bf16* __restrict__ A, int lda,
    const bf16* __restrict__ BT, int ldb,
    OUT* __restrict__ C, int ldc, int K)
{
    __shared__ char smem[VEC ? (128 * EPI_LD * 2) : 16384];
    bf16* As = (bf16*)smem;
    bf16* Bs = (bf16*)(smem + 8192);

    const int u   = blockIdx.x;
    const int xcd = u & 7;
    const int s   = u >> 3;
    const int mt  = s & 63;
    const int col = xcd + 8 * (s >> 6);

    const int tid  = threadIdx.x;
    const int wave = tid >> 6;
    const int lane = tid & 63;
    const int row0 = mt * 128;
    const int col0 = col * 128;

    const int sr = lane >> 2;
    const int sc = (lane & 3) * 8;
    const bf16* agp0 = A  + (long)(row0 + 16 * wave       + sr) * lda + sc;
    const bf16* agp1 = A  + (long)(row0 + 16 * (wave + 4) + sr) * lda + sc;
    const bf16* bgp0 = BT + (long)(col0 + 16 * wave       + sr) * ldb + sc;
    const bf16* bgp1 = BT + (long)(col0 + 16 * (wave + 4) + sr) * ldb + sc;
    bf16* asl0 = As + (long)wave * 512;
    bf16* asl1 = As + (long)(wave + 4) * 512;
    bf16* bsl0 = Bs + (long)wave * 512;
    bf16* bsl1 = Bs + (long)(wave + 4) * 512;

    const int mi_base = (wave >> 1) * 64;
    const int ni_base = (wave & 1) * 64;
    const int fr = lane & 15;
    const int fq = lane >> 4;

    floatx4 acc[4][4] = {};

    for (int k0 = 0; k0 < K; k0 += 32) {
        __syncthreads();
        gload_lds16(agp0 + k0, (void*)asl0);
        gload_lds16(agp1 + k0, (void*)asl1);
        gload_lds16(bgp0 + k0, (void*)bsl0);
        gload_lds16(bgp1 + k0, (void*)bsl1);
        __syncthreads();

        bf16x8 af[4], bfr[4];
#pragma unroll
        for (int i = 0; i < 4; ++i) {
            af[i]  = *(const bf16x8*)(As + (mi_base + i * 16 + fr) * 32 + fq * 8);
            bfr[i] = *(const bf16x8*)(Bs + (ni_base + i * 16 + fr) * 32 + fq * 8);
        }
#pragma unroll
        for (int i = 0; i < 4; ++i)
#pragma unroll
            for (int j = 0; j < 4; ++j)
                acc[i][j] = __builtin_amdgcn_mfma_f32_16x16x32_bf16(
                    af[i], bfr[j], acc[i][j], 0, 0, 0);
    }

    if (VEC) {
        __syncthreads();               // staging LDS dead; reuse as out-tile
        bf16* tile = (bf16*)smem;
#pragma unroll
        for (int i = 0; i < 4; ++i)
#pragma unroll
            for (int j = 0; j < 4; ++j)
#pragma unroll
                for (int r = 0; r < 4; ++r) {
                    const int rl = mi_base + i * 16 + fq * 4 + r;
                    const int cl = ni_base + j * 16 + fr;
                    tile[rl * EPI_LD + cl] = (bf16)acc[i][j][r];
                }
        __syncthreads();
#pragma unroll
        for (int k = 0; k < 8; ++k) {
            const int rl = (tid >> 3) + 32 * (k >> 1);
            const int cl = (tid & 7) * 8 + 64 * (k & 1);
            const bf16x8 v = *(const bf16x8*)(tile + rl * EPI_LD + cl);
            *(bf16x8*)((bf16*)C + (long)(row0 + rl) * ldc + col0 + cl) = v;
        }
    } else {
#pragma unroll
        for (int i = 0; i < 4; ++i)
#pragma unroll
            for (int j = 0; j < 4; ++j)
#pragma unroll
                for (int r = 0; r < 4; ++r) {
                    const long row = row0 + mi_base + i * 16 + fq * 4 + r;
                    const long cg  = col0 + ni_base + j * 16 + fr;
                    C[row * ldc + cg] = (OUT)acc[i][j][r];
                }
    }
}

// ---------------------------------------------------------------------------
// 7) sparse grouped GEMM on sorted A: expert g rows are contiguous in Xs.
//    Scaled bf16 partials -> compact unpadded slot buffer ysp.
//    1-D grid 8*64*32; same-B-tile blocks pinned to one XCD.
// ---------------------------------------------------------------------------
__global__ __launch_bounds__(256, 4) void gemm_sparse(
    const bf16* __restrict__ Xs,   // [padded slots][E_DIM]
    const bf16* __restrict__ WiT,  // [O_DIM][8192]
    const int* __restrict__ cnt,
    const int* __restrict__ off,
    const int* __restrict__ offp,
    const float* __restrict__ scl,
    bf16* __restrict__ ysp)        // [2*N_TOK][O_DIM]
{
    const int u    = blockIdx.x;
    const int xcd  = u & 7;
    const int s    = u >> 3;
    const int mt   = s & 63;
    const int pair = xcd + 8 * (s >> 6);   // [0,256)
    const int g    = pair & 7;
    const int col  = pair >> 3;            // [0,32)

    const int cg   = cnt[g];
    const int cgp  = offp[g + 1] - offp[g];
    const int m0   = mt * 128;
    if (m0 >= cgp) return;

    __shared__ char smem[128 * EPI_LD * 2];
    bf16* As = (bf16*)smem;
    bf16* Bs = (bf16*)(smem + 8192);

    const int tid  = threadIdx.x;
    const int wave = tid >> 6;
    const int lane = tid & 63;
    const int col0 = col * 128;

    const int sr = lane >> 2;
    const int sc = (lane & 3) * 8;
    const bf16* A = Xs + (long)(offp[g] + m0) * E_DIM;
    const bf16* agp0 = A + (long)(16 * wave       + sr) * E_DIM + sc;
    const bf16* agp1 = A + (long)(16 * (wave + 4) + sr) * E_DIM + sc;
    const bf16* bgp0 = WiT + (long)(col0 + 16 * wave       + sr) * 8192 + g * E_DIM + sc;
    const bf16* bgp1 = WiT + (long)(col0 + 16 * (wave + 4) + sr) * 8192 + g * E_DIM + sc;
    bf16* asl0 = As + (long)wave * 512;
    bf16* asl1 = As + (long)(wave + 4) * 512;
    bf16* bsl0 = Bs + (long)wave * 512;
    bf16* bsl1 = Bs + (long)(wave + 4) * 512;

    const int mi_base = (wave >> 1) * 64;
    const int ni_base = (wave & 1) * 64;
    const int fr = lane & 15;
    const int fq = lane >> 4;

    floatx4 acc[4][4] = {};

    for (int k0 = 0; k0 < E_DIM; k0 += 32) {
        __syncthreads();
        gload_lds16(agp0 + k0, (void*)asl0);
        gload_lds16(agp1 + k0, (void*)asl1);
        gload_lds16(bgp0 + k0, (void*)bsl0);
        gload_lds16(bgp1 + k0, (void*)bsl1);
        __syncthreads();

        bf16x8 af[4], bfr[4];
#pragma unroll
        for (int i = 0; i < 4; ++i) {
            af[i]  = *(const bf16x8*)(As + (mi_base + i * 16 + fr) * 32 + fq * 8);
            bfr[i] = *(const bf16x8*)(Bs + (ni_base + i * 16 + fr) * 32 + fq * 8);
        }
#pragma unroll
        for (int i = 0; i < 4; ++i)
#pragma unroll
            for (int j = 0; j < 4; ++j)
                acc[i][j] = __builtin_amdgcn_mfma_f32_16x16x32_bf16(
                    af[i], bfr[j], acc[i][j], 0, 0, 0);
    }

    // epilogue: scale per row, stage bf16 tile in LDS, vector store valid rows
    const float* sclg = scl + g * N_TOK;
    const int cl = cg - 1;
    __syncthreads();
    bf16* tile = (bf16*)smem;
#pragma unroll
    for (int i = 0; i < 4; ++i) {
#pragma unroll
        for (int r = 0; r < 4; ++r) {
            const int rl = mi_base + i * 16 + fq * 4 + r;
            const int gm = m0 + rl;
            const float sv = sclg[gm > cl ? cl : gm];
#pragma unroll
            for (int j = 0; j < 4; ++j) {
                const int clc = ni_base + j * 16 + fr;
                tile[rl * EPI_LD + clc] = (bf16)(sv * acc[i][j][r]);
            }
        }
    }
    __syncthreads();
    const long obase = off[g] + m0;
#pragma unroll
    for (int k = 0; k < 8; ++k) {
        const int rl = (tid >> 3) + 32 * (k >> 1);
        const int cc = (tid & 7) * 8 + 64 * (k & 1);
        if (m0 + rl < cg) {
            const bf16x8 v = *(const bf16x8*)(tile + rl * EPI_LD + cc);
            *(bf16x8*)(ysp + (obase + rl) * O_DIM + col0 + cc) = v;
        }
    }
}

// ---------------------------------------------------------------------------
// 8) h = bf16(relu(ybase + ysp[slot0] + ysp[slot1])^2); one block per token
// ---------------------------------------------------------------------------
__global__ __launch_bounds__(256) void relu2_gather(
    const bf16* __restrict__ Yb,   // [N_TOK][O_DIM]
    const bf16* __restrict__ ysp,  // [2*N_TOK][O_DIM]
    const int* __restrict__ pos,   // [N_TOK][2]
    const int* __restrict__ off,   // [G_DIM]
    bf16* __restrict__ H)          // [N_TOK][O_DIM]
{
    const int t  = blockIdx.x;
    const int p0 = pos[t * 2];
    const int p1 = pos[t * 2 + 1];
    const long r0 = off[p0 >> 16] + (p0 & 0xffff);
    const long r1 = off[p1 >> 16] + (p1 & 0xffff);
    const int c = threadIdx.x * 16;

    const bf16* yb = Yb + (long)t * O_DIM + c;
    const bf16* s0 = ysp + r0 * O_DIM + c;
    const bf16* s1 = ysp + r1 * O_DIM + c;
    bf16* hp = H + (long)t * O_DIM + c;

#pragma unroll
    for (int h = 0; h < 2; ++h) {
        const bf16x8 a = *(const bf16x8*)(yb + h * 8);
        const bf16x8 b = *(const bf16x8*)(s0 + h * 8);
        const bf16x8 d = *(const bf16x8*)(s1 + h * 8);
        bf16x8 o;
#pragma unroll
        for (int k = 0; k < 8; ++k) {
            float v = (float)a[k] + (float)b[k] + (float)d[k];
            v = fmaxf(v, 0.f);
            o[k] = (bf16)(v * v);
        }
        *(bf16x8*)(hp + h * 8) = o;
    }
}

// ---------------------------------------------------------------------------
extern "C" void kernel_launch(void* const* d_in, const int* in_sizes, int n_in,
                              void* d_out, int out_size, void* d_ws, size_t ws_size,
                              hipStream_t stream)
{
    const float* X  = (const float*)d_in[0];  // [4,2048,1024]
    const float* WG = (const float*)d_in[1];  // [1024,8]
    const float* Wi = (const float*)d_in[2];  // [8,1024,4096] == [8192][4096]
    const float* dn = (const float*)d_in[3];  // [4096,1024]
    float* out = (float*)d_out;               // [8192][1024] fp32

    char* ws = (char*)d_ws;
    const long MB = 1l << 20;
    int*   cnt   = (int*)ws;                        // 32 B (zeroed)
    int*   off   = (int*)(ws + 1024);               // 32 B
    int*   offp  = (int*)(ws + 2048);               // 36 B
    int*   pos   = (int*)(ws + 4096);               // 64 KB
    int*   tok   = (int*)(ws + 128 * 1024);         // 256 KB
    float* scl   = (float*)(ws + 448 * 1024);       // 256 KB
    bf16*  dnT   = (bf16*)(ws + 1 * MB);            // 8 MB
    bf16*  WiT   = (bf16*)(ws + 9 * MB);            // 64 MB
    bf16*  Hh    = (bf16*)(ws + 9 * MB);            // 64 MB (aliases WiT; dead by then)
    bf16*  Xs    = (bf16*)(ws + 73 * MB);           // 34 MB (17408 slots)
    bf16*  Yb    = (bf16*)(ws + 107 * MB);          // 64 MB
    bf16*  ysp   = (bf16*)(ws + 171 * MB);          // 128 MB -> 299 MB high water
    bf16*  Xb    = (bf16*)(ws + 171 * MB);          // 16 MB (overlaid by ysp AFTER gather)
    bf16*  WsumT = (bf16*)(ws + 187 * MB);          // 8 MB  (overlaid by ysp after base gemm)

    hipMemsetAsync(cnt, 0, 64, stream);
    gate_kernel<<<dim3(N_TOK / 4), dim3(256), 0, stream>>>(X, WG, cnt, tok, scl, pos);
    prefix_kernel<<<dim3(1), dim3(64), 0, stream>>>(cnt, off, offp);
    convert_x<<<dim3(N_TOK * E_DIM / 1024), dim3(256), 0, stream>>>(X, Xb);
    transpose_conv<<<dim3(8192 / 64, O_DIM / 64), dim3(256), 0, stream>>>(Wi, WiT, 8192, O_DIM);
    transpose_conv<<<dim3(O_DIM / 64, E_DIM / 64), dim3(256), 0, stream>>>(dn, dnT, O_DIM, E_DIM);
    wsum_kernel<<<dim3(O_DIM), dim3(256), 0, stream>>>(WiT, WsumT);
    // y_base = Xb @ WsumT^T  (bf16 out, vec epilogue); 64 mtiles x 32 coltiles
    gemm_mt<bf16, true><<<dim3(64 * 32), dim3(256), 0, stream>>>(
        Xb, E_DIM, WsumT, E_DIM, Yb, O_DIM, E_DIM);
    // expert-sorted padded copy of X (after base gemm: Xb/WsumT then dead)
    gather_rows<<<dim3(17408), dim3(128), 0, stream>>>(Xb, cnt, offp, tok, Xs);
    // slot partials: scale * sortedX @ Wi[g]  (ysp overlays Xb/WsumT)
    gemm_sparse<<<dim3(G_DIM * 64 * 32), dim3(256), 0, stream>>>(
        Xs, WiT, cnt, off, offp, scl, ysp);
    relu2_gather<<<dim3(N_TOK), dim3(256), 0, stream>>>(Yb, ysp, pos, off, Hh);
    // out = Hh @ dnT^T  (fp32 out); 64 mtiles x 8 coltiles
    gemm_mt<float, false><<<dim3(64 * 8), dim3(256), 0, stream>>>(
        Hh, O_DIM, dnT, O_DIM, out, E_DIM, O_DIM);
}

// Round 5
// 734.005 us; speedup vs baseline: 1.5488x; 1.2389x over previous
//
#include <hip/hip_runtime.h>
#include <hip/hip_bf16.h>
#include <math.h>

typedef __bf16 bf16;
typedef __bf16 bf16x4 __attribute__((ext_vector_type(4)));
typedef __bf16 bf16x8 __attribute__((ext_vector_type(8)));
typedef float  floatx4 __attribute__((ext_vector_type(4)));

#define N_TOK 8192   // B*S
#define E_DIM 1024
#define G_DIM 8
#define O_DIM 4096
#define EPI_LD 132   // padded leading dim of epilogue LDS tile (bf16)

__device__ __forceinline__ void gload_lds16(const void* g, void* l) {
    __builtin_amdgcn_global_load_lds(
        (__attribute__((address_space(1))) void*)(g),
        (__attribute__((address_space(3))) void*)(l),
        16, 0, 0);
}

// ---------------------------------------------------------------------------
// 1) gate = X @ WG; top-2. NO atomics: writes per-entry expert id + scale.
//    One wave per token; WG transposed in LDS for conflict-free b128 reads.
// ---------------------------------------------------------------------------
__global__ __launch_bounds__(256) void gate_compute(
    const float* __restrict__ X,   // [N_TOK][E_DIM]
    const float* __restrict__ WG,  // [E_DIM][G_DIM]
    int* __restrict__ sel,         // [N_TOK*2] expert id
    float* __restrict__ sval)      // [N_TOK*2] sigmoid-0.5
{
    __shared__ float lwgT[G_DIM * E_DIM];   // [g][e], 32 KB
    const int tid  = threadIdx.x;
    const int wave = tid >> 6;
    const int lane = tid & 63;

    // stage WG transposed: 2048 float4s of WG, each covers (e = i/2, ghalf = i&1)
#pragma unroll
    for (int k = 0; k < 8; ++k) {
        const int i = k * 256 + tid;
        const float4 v = *(const float4*)(WG + i * 4);
        const int e  = i >> 1;
        const int g0 = (i & 1) * 4;
        lwgT[(g0 + 0) * E_DIM + e] = v.x;
        lwgT[(g0 + 1) * E_DIM + e] = v.y;
        lwgT[(g0 + 2) * E_DIM + e] = v.z;
        lwgT[(g0 + 3) * E_DIM + e] = v.w;
    }
    __syncthreads();

    const int t = blockIdx.x * 4 + wave;
    float acc[G_DIM];
#pragma unroll
    for (int g = 0; g < G_DIM; ++g) acc[g] = 0.f;

#pragma unroll
    for (int it = 0; it < 4; ++it) {
        const int e0 = it * 256 + lane * 4;
        const float4 xv = *(const float4*)(X + (long)t * E_DIM + e0);
#pragma unroll
        for (int g = 0; g < G_DIM; ++g) {
            const float4 wv = *(const float4*)(lwgT + g * E_DIM + e0);
            acc[g] += xv.x * wv.x + xv.y * wv.y + xv.z * wv.z + xv.w * wv.w;
        }
    }
#pragma unroll
    for (int g = 0; g < G_DIM; ++g) {
        float v = acc[g];
#pragma unroll
        for (int off = 32; off > 0; off >>= 1) v += __shfl_down(v, off, 64);
        acc[g] = v;  // valid on lane 0
    }
    if (lane == 0) {
        int i1 = 0;
#pragma unroll
        for (int g = 1; g < G_DIM; ++g) if (acc[g] > acc[i1]) i1 = g;
        int i2 = (i1 == 0) ? 1 : 0;
#pragma unroll
        for (int g = 0; g < G_DIM; ++g)
            if (g != i1 && g != i2 && acc[g] > acc[i2]) i2 = g;
#pragma unroll
        for (int s = 0; s < 2; ++s) {
            const int g = s ? i2 : i1;
            sel[t * 2 + s]  = g;
            sval[t * 2 + s] = 1.f / (1.f + expf(-acc[g])) - 0.5f;
        }
    }
}

// ---------------------------------------------------------------------------
// 1b) routing: ballot histogram + prefix + stable scatter. 1 block x 1024.
//     Produces cnt/off/offp, tok/scl (expert-major), pos. No atomics.
// ---------------------------------------------------------------------------
__global__ __launch_bounds__(1024) void route_kernel(
    const int* __restrict__ sel, const float* __restrict__ sval,
    int* __restrict__ cnt, int* __restrict__ off, int* __restrict__ offp,
    int* __restrict__ tok, float* __restrict__ scl, int* __restrict__ pos)
{
    __shared__ int hcnt[16][G_DIM];
    __shared__ int wbase[16][G_DIM];
    const int tid  = threadIdx.x;
    const int w    = tid >> 6;
    const int lane = tid & 63;
    const unsigned long long below = ((unsigned long long)1 << lane) - 1;

    // pass 1: per-wave-segment histogram (each wave owns 1024 entries)
    int c0[G_DIM];
#pragma unroll
    for (int g = 0; g < G_DIM; ++g) c0[g] = 0;
    for (int c = 0; c < 16; ++c) {
        const int g = sel[w * 1024 + c * 64 + lane];
#pragma unroll
        for (int gg = 0; gg < G_DIM; ++gg)
            c0[gg] += __popcll(__ballot(g == gg));
    }
    if (lane == 0)
#pragma unroll
        for (int g = 0; g < G_DIM; ++g) hcnt[w][g] = c0[g];
    __syncthreads();

    if (tid == 0) {
        int tot[G_DIM];
#pragma unroll
        for (int g = 0; g < G_DIM; ++g) {
            int a = 0;
            for (int ww = 0; ww < 16; ++ww) { wbase[ww][g] = a; a += hcnt[ww][g]; }
            tot[g] = a; cnt[g] = a;
        }
        int a = 0, b = 0;
#pragma unroll
        for (int g = 0; g < G_DIM; ++g) {
            off[g]  = a; a += tot[g];
            offp[g] = b; b += (tot[g] + 127) & ~127;
        }
        offp[G_DIM] = b;
    }
    __syncthreads();

    // pass 2: stable rank within wave segment, write routed arrays
    int run[G_DIM];
#pragma unroll
    for (int g = 0; g < G_DIM; ++g) run[g] = 0;
    for (int c = 0; c < 16; ++c) {
        const int idx = w * 1024 + c * 64 + lane;
        const int g   = sel[idx];
        const float sv = sval[idx];
        int myrank = 0;
#pragma unroll
        for (int gg = 0; gg < G_DIM; ++gg) {
            const unsigned long long m = __ballot(g == gg);
            const int r = run[gg] + __popcll(m & below);
            if (g == gg) myrank = r;
            run[gg] += __popcll(m);
        }
        const int p = wbase[w][g] + myrank;
        tok[g * N_TOK + p] = idx >> 1;
        scl[g * N_TOK + p] = sv;
        pos[idx] = (g << 16) | p;
    }
}

// ---------------------------------------------------------------------------
// 2) X fp32 -> bf16
// ---------------------------------------------------------------------------
__global__ __launch_bounds__(256) void convert_x(
    const float* __restrict__ X, bf16* __restrict__ Xb)
{
    const long i = ((long)blockIdx.x * 256 + threadIdx.x) * 4;
    const float4 v = *(const float4*)(X + i);
    bf16x4 o;
    o[0] = (bf16)v.x; o[1] = (bf16)v.y; o[2] = (bf16)v.z; o[3] = (bf16)v.w;
    *(bf16x4*)(Xb + i) = o;
}

// ---------------------------------------------------------------------------
// 3) transpose + fp32->bf16: S[R][C] -> D[C][R]
// ---------------------------------------------------------------------------
__global__ __launch_bounds__(256) void transpose_conv(
    const float* __restrict__ S, bf16* __restrict__ D, int R, int C)
{
    __shared__ float tile[64][65];
    const int r0  = blockIdx.x * 64;
    const int c0  = blockIdx.y * 64;
    const int tid = threadIdx.x;
    const int tr  = tid >> 4;          // 0..15
    const int tc4 = (tid & 15) * 4;    // 0..60

#pragma unroll
    for (int p = 0; p < 4; ++p) {
        const int r = p * 16 + tr;
        const float4 v = *(const float4*)(S + (long)(r0 + r) * C + c0 + tc4);
        tile[r][tc4 + 0] = v.x;
        tile[r][tc4 + 1] = v.y;
        tile[r][tc4 + 2] = v.z;
        tile[r][tc4 + 3] = v.w;
    }
    __syncthreads();
#pragma unroll
    for (int p = 0; p < 4; ++p) {
        const int c = p * 16 + tr;     // source col == dest row
        bf16x4 o;
        o[0] = (bf16)tile[tc4 + 0][c];
        o[1] = (bf16)tile[tc4 + 1][c];
        o[2] = (bf16)tile[tc4 + 2][c];
        o[3] = (bf16)tile[tc4 + 3][c];
        *(bf16x4*)(D + (long)(c0 + c) * R + r0 + tc4) = o;
    }
}

// ---------------------------------------------------------------------------
// 4) WsumT[o][e] = 0.5 * sum_g WiT[o][g*1024+e]   (bf16)
// ---------------------------------------------------------------------------
__global__ __launch_bounds__(256) void wsum_kernel(
    const bf16* __restrict__ WiT, bf16* __restrict__ WsumT)
{
    const int o  = blockIdx.x;
    const int e4 = threadIdx.x * 4;
    float a0 = 0.f, a1 = 0.f, a2 = 0.f, a3 = 0.f;
#pragma unroll
    for (int g = 0; g < G_DIM; ++g) {
        const bf16x4 v = *(const bf16x4*)(WiT + (long)o * 8192 + g * E_DIM + e4);
        a0 += (float)v[0]; a1 += (float)v[1]; a2 += (float)v[2]; a3 += (float)v[3];
    }
    bf16x4 w;
    w[0] = (bf16)(0.5f * a0); w[1] = (bf16)(0.5f * a1);
    w[2] = (bf16)(0.5f * a2); w[3] = (bf16)(0.5f * a3);
    *(bf16x4*)(WsumT + (long)o * E_DIM + e4) = w;
}

// ---------------------------------------------------------------------------
// 5) gather rows of Xb into expert-sorted, 128-padded Xs. One block per slot.
// ---------------------------------------------------------------------------
__global__ __launch_bounds__(128) void gather_rows(
    const bf16* __restrict__ Xb, const int* __restrict__ cnt,
    const int* __restrict__ offp, const int* __restrict__ tok,
    bf16* __restrict__ Xs)
{
    const int slot = blockIdx.x;
    if (slot >= offp[G_DIM]) return;
    int g = 0;
    while (slot >= offp[g + 1]) ++g;
    const int p = slot - offp[g];
    bf16* dst = Xs + (long)slot * E_DIM + threadIdx.x * 8;
    if (p < cnt[g]) {
        const bf16* src = Xb + (long)tok[g * N_TOK + p] * E_DIM + threadIdx.x * 8;
        *(bf16x8*)dst = *(const bf16x8*)src;
    } else {
        bf16x8 z = {};
        *(bf16x8*)dst = z;
    }
}

// ---------------------------------------------------------------------------
// 6) generic dense bf16 GEMM, 1-D grid with XCD-aware decode.
//    A [M][lda], BT [N][ldb] row-major bf16. 128x128 tile, BK=32.
//    VEC: bf16 out via LDS-staged vectorized epilogue. else fp32 scalar.
//    grid.x = 64 (m-tiles) * NCT (col-tiles); NCT multiple of 8.
// ---------------------------------------------------------------------------
template <typename OUT, bool VEC>
__global__ __launch_bounds__(256, 4) void gemm_mt(
    const bf16* __restrict__ A, int lda,
    const bf16* __restrict__ BT, int ldb,
    OUT* __restrict__ C, int ldc, int K)
{
    __shared__ char smem[VEC ? (128 * EPI_LD * 2) : 16384];
    bf16* As = (bf16*)smem;
    bf16* Bs = (bf16*)(smem + 8192);

    const int u   = blockIdx.x;
    const int xcd = u & 7;
    const int s   = u >> 3;
    const int mt  = s & 63;
    const int col = xcd + 8 * (s >> 6);

    const int tid  = threadIdx.x;
    const int wave = tid >> 6;
    const int lane = tid & 63;
    const int row0 = mt * 128;
    const int col0 = col * 128;

    const int sr = lane >> 2;
    const int sc = (lane & 3) * 8;
    const bf16* agp0 = A  + (long)(row0 + 16 * wave       + sr) * lda + sc;
    const bf16* agp1 = A  + (long)(row0 + 16 * (wave + 4) + sr) * lda + sc;
    const bf16* bgp0 = BT + (long)(col0 + 16 * wave       + sr) * ldb + sc;
    const bf16* bgp1 = BT + (long)(col0 + 16 * (wave + 4) + sr) * ldb + sc;
    bf16* asl0 = As + (long)wave * 512;
    bf16* asl1 = As + (long)(wave + 4) * 512;
    bf16* bsl0 = Bs + (long)wave * 512;
    bf16* bsl1 = Bs + (long)(wave + 4) * 512;

    const int mi_base = (wave >> 1) * 64;
    const int ni_base = (wave & 1) * 64;
    const int fr = lane & 15;
    const int fq = lane >> 4;

    floatx4 acc[4][4] = {};

    for (int k0 = 0; k0 < K; k0 += 32) {
        __syncthreads();
        gload_lds16(agp0 + k0, (void*)asl0);
        gload_lds16(agp1 + k0, (void*)asl1);
        gload_lds16(bgp0 + k0, (void*)bsl0);
        gload_lds16(bgp1 + k0, (void*)bsl1);
        __syncthreads();

        bf16x8 af[4], bfr[4];
#pragma unroll
        for (int i = 0; i < 4; ++i) {
            af[i]  = *(const bf16x8*)(As + (mi_base + i * 16 + fr) * 32 + fq * 8);
            bfr[i] = *(const bf16x8*)(Bs + (ni_base + i * 16 + fr) * 32 + fq * 8);
        }
#pragma unroll
        for (int i = 0; i < 4; ++i)
#pragma unroll
            for (int j = 0; j < 4; ++j)
                acc[i][j] = __builtin_amdgcn_mfma_f32_16x16x32_bf16(
                    af[i], bfr[j], acc[i][j], 0, 0, 0);
    }

    if (VEC) {
        __syncthreads();               // staging LDS dead; reuse as out-tile
        bf16* tile = (bf16*)smem;
#pragma unroll
        for (int i = 0; i < 4; ++i)
#pragma unroll
            for (int j = 0; j < 4; ++j)
#pragma unroll
                for (int r = 0; r < 4; ++r) {
                    const int rl = mi_base + i * 16 + fq * 4 + r;
                    const int cl = ni_base + j * 16 + fr;
                    tile[rl * EPI_LD + cl] = (bf16)acc[i][j][r];
                }
        __syncthreads();
#pragma unroll
        for (int k = 0; k < 8; ++k) {
            const int rl = (tid >> 3) + 32 * (k >> 1);
            const int cl = (tid & 7) * 8 + 64 * (k & 1);
            const bf16x8 v = *(const bf16x8*)(tile + rl * EPI_LD + cl);
            *(bf16x8*)((bf16*)C + (long)(row0 + rl) * ldc + col0 + cl) = v;
        }
    } else {
#pragma unroll
        for (int i = 0; i < 4; ++i)
#pragma unroll
            for (int j = 0; j < 4; ++j)
#pragma unroll
                for (int r = 0; r < 4; ++r) {
                    const long row = row0 + mi_base + i * 16 + fq * 4 + r;
                    const long cg  = col0 + ni_base + j * 16 + fr;
                    C[row * ldc + cg] = (OUT)acc[i][j][r];
                }
    }
}

// ---------------------------------------------------------------------------
// 7) sparse grouped GEMM on sorted A: expert g rows are contiguous in Xs.
//    Scaled bf16 partials -> compact unpadded slot buffer ysp.
//    1-D grid 8*64*32; same-B-tile blocks pinned to one XCD.
// ---------------------------------------------------------------------------
__global__ __launch_bounds__(256, 4) void gemm_sparse(
    const bf16* __restrict__ Xs,   // [padded slots][E_DIM]
    const bf16* __restrict__ WiT,  // [O_DIM][8192]
    const int* __restrict__ cnt,
    const int* __restrict__ off,
    const int* __restrict__ offp,
    const float* __restrict__ scl,
    bf16* __restrict__ ysp)        // [2*N_TOK][O_DIM]
{
    const int u    = blockIdx.x;
    const int xcd  = u & 7;
    const int s    = u >> 3;
    const int mt   = s & 63;
    const int pair = xcd + 8 * (s >> 6);   // [0,256)
    const int g    = pair & 7;
    const int col  = pair >> 3;            // [0,32)

    const int cg   = cnt[g];
    const int cgp  = offp[g + 1] - offp[g];
    const int m0   = mt * 128;
    if (m0 >= cgp) return;

    __shared__ char smem[128 * EPI_LD * 2];
    bf16* As = (bf16*)smem;
    bf16* Bs = (bf16*)(smem + 8192);

    const int tid  = threadIdx.x;
    const int wave = tid >> 6;
    const int lane = tid & 63;
    const int col0 = col * 128;

    const int sr = lane >> 2;
    const int sc = (lane & 3) * 8;
    const bf16* A = Xs + (long)(offp[g] + m0) * E_DIM;
    const bf16* agp0 = A + (long)(16 * wave       + sr) * E_DIM + sc;
    const bf16* agp1 = A + (long)(16 * (wave + 4) + sr) * E_DIM + sc;
    const bf16* bgp0 = WiT + (long)(col0 + 16 * wave       + sr) * 8192 + g * E_DIM + sc;
    const bf16* bgp1 = WiT + (long)(col0 + 16 * (wave + 4) + sr) * 8192 + g * E_DIM + sc;
    bf16* asl0 = As + (long)wave * 512;
    bf16* asl1 = As + (long)(wave + 4) * 512;
    bf16* bsl0 = Bs + (long)wave * 512;
    bf16* bsl1 = Bs + (long)(wave + 4) * 512;

    const int mi_base = (wave >> 1) * 64;
    const int ni_base = (wave & 1) * 64;
    const int fr = lane & 15;
    const int fq = lane >> 4;

    floatx4 acc[4][4] = {};

    for (int k0 = 0; k0 < E_DIM; k0 += 32) {
        __syncthreads();
        gload_lds16(agp0 + k0, (void*)asl0);
        gload_lds16(agp1 + k0, (void*)asl1);
        gload_lds16(bgp0 + k0, (void*)bsl0);
        gload_lds16(bgp1 + k0, (void*)bsl1);
        __syncthreads();

        bf16x8 af[4], bfr[4];
#pragma unroll
        for (int i = 0; i < 4; ++i) {
            af[i]  = *(const bf16x8*)(As + (mi_base + i * 16 + fr) * 32 + fq * 8);
            bfr[i] = *(const bf16x8*)(Bs + (ni_base + i * 16 + fr) * 32 + fq * 8);
        }
#pragma unroll
        for (int i = 0; i < 4; ++i)
#pragma unroll
            for (int j = 0; j < 4; ++j)
                acc[i][j] = __builtin_amdgcn_mfma_f32_16x16x32_bf16(
                    af[i], bfr[j], acc[i][j], 0, 0, 0);
    }

    // epilogue: scale per row, stage bf16 tile in LDS, vector store valid rows
    const float* sclg = scl + g * N_TOK;
    const int cl = cg - 1;
    __syncthreads();
    bf16* tile = (bf16*)smem;
#pragma unroll
    for (int i = 0; i < 4; ++i) {
#pragma unroll
        for (int r = 0; r < 4; ++r) {
            const int rl = mi_base + i * 16 + fq * 4 + r;
            const int gm = m0 + rl;
            const float sv = sclg[gm > cl ? cl : gm];
#pragma unroll
            for (int j = 0; j < 4; ++j) {
                const int clc = ni_base + j * 16 + fr;
                tile[rl * EPI_LD + clc] = (bf16)(sv * acc[i][j][r]);
            }
        }
    }
    __syncthreads();
    const long obase = off[g] + m0;
#pragma unroll
    for (int k = 0; k < 8; ++k) {
        const int rl = (tid >> 3) + 32 * (k >> 1);
        const int cc = (tid & 7) * 8 + 64 * (k & 1);
        if (m0 + rl < cg) {
            const bf16x8 v = *(const bf16x8*)(tile + rl * EPI_LD + cc);
            *(bf16x8*)(ysp + (obase + rl) * O_DIM + col0 + cc) = v;
        }
    }
}

// ---------------------------------------------------------------------------
// 8) h = bf16(relu(ybase + ysp[slot0] + ysp[slot1])^2); one block per token
// ---------------------------------------------------------------------------
__global__ __launch_bounds__(256) void relu2_gather(
    const bf16* __restrict__ Yb,   // [N_TOK][O_DIM]
    const bf16* __restrict__ ysp,  // [2*N_TOK][O_DIM]
    const int* __restrict__ pos,   // [N_TOK][2]
    const int* __restrict__ off,   // [G_DIM]
    bf16* __restrict__ H)          // [N_TOK][O_DIM]
{
    const int t  = blockIdx.x;
    const int p0 = pos[t * 2];
    const int p1 = pos[t * 2 + 1];
    const long r0 = off[p0 >> 16] + (p0 & 0xffff);
    const long r1 = off[p1 >> 16] + (p1 & 0xffff);
    const int c = threadIdx.x * 16;

    const bf16* yb = Yb + (long)t * O_DIM + c;
    const bf16* s0 = ysp + r0 * O_DIM + c;
    const bf16* s1 = ysp + r1 * O_DIM + c;
    bf16* hp = H + (long)t * O_DIM + c;

#pragma unroll
    for (int h = 0; h < 2; ++h) {
        const bf16x8 a = *(const bf16x8*)(yb + h * 8);
        const bf16x8 b = *(const bf16x8*)(s0 + h * 8);
        const bf16x8 d = *(const bf16x8*)(s1 + h * 8);
        bf16x8 o;
#pragma unroll
        for (int k = 0; k < 8; ++k) {
            float v = (float)a[k] + (float)b[k] + (float)d[k];
            v = fmaxf(v, 0.f);
            o[k] = (bf16)(v * v);
        }
        *(bf16x8*)(hp + h * 8) = o;
    }
}

// ---------------------------------------------------------------------------
extern "C" void kernel_launch(void* const* d_in, const int* in_sizes, int n_in,
                              void* d_out, int out_size, void* d_ws, size_t ws_size,
                              hipStream_t stream)
{
    const float* X  = (const float*)d_in[0];  // [4,2048,1024]
    const float* WG = (const float*)d_in[1];  // [1024,8]
    const float* Wi = (const float*)d_in[2];  // [8,1024,4096] == [8192][4096]
    const float* dn = (const float*)d_in[3];  // [4096,1024]
    float* out = (float*)d_out;               // [8192][1024] fp32

    char* ws = (char*)d_ws;
    const long MB = 1l << 20;
    int*   cnt   = (int*)ws;                        // 32 B
    int*   off   = (int*)(ws + 1024);               // 32 B
    int*   offp  = (int*)(ws + 2048);               // 36 B
    int*   pos   = (int*)(ws + 4096);               // 64 KB
    int*   tok   = (int*)(ws + 128 * 1024);         // 256 KB
    float* scl   = (float*)(ws + 448 * 1024);       // 256 KB
    int*   sel   = (int*)(ws + 704 * 1024);         // 64 KB
    float* sval  = (float*)(ws + 768 * 1024);       // 64 KB
    bf16*  dnT   = (bf16*)(ws + 1 * MB);            // 8 MB
    bf16*  WiT   = (bf16*)(ws + 9 * MB);            // 64 MB
    bf16*  Hh    = (bf16*)(ws + 9 * MB);            // 64 MB (aliases WiT; dead by then)
    bf16*  Xs    = (bf16*)(ws + 73 * MB);           // 34 MB (17408 slots)
    bf16*  Yb    = (bf16*)(ws + 107 * MB);          // 64 MB
    bf16*  ysp   = (bf16*)(ws + 171 * MB);          // 128 MB -> 299 MB high water
    bf16*  Xb    = (bf16*)(ws + 171 * MB);          // 16 MB (overlaid by ysp AFTER gather)
    bf16*  WsumT = (bf16*)(ws + 187 * MB);          // 8 MB  (overlaid by ysp after base gemm)

    gate_compute<<<dim3(N_TOK / 4), dim3(256), 0, stream>>>(X, WG, sel, sval);
    route_kernel<<<dim3(1), dim3(1024), 0, stream>>>(sel, sval, cnt, off, offp,
                                                     tok, scl, pos);
    convert_x<<<dim3(N_TOK * E_DIM / 1024), dim3(256), 0, stream>>>(X, Xb);
    transpose_conv<<<dim3(8192 / 64, O_DIM / 64), dim3(256), 0, stream>>>(Wi, WiT, 8192, O_DIM);
    transpose_conv<<<dim3(O_DIM / 64, E_DIM / 64), dim3(256), 0, stream>>>(dn, dnT, O_DIM, E_DIM);
    wsum_kernel<<<dim3(O_DIM), dim3(256), 0, stream>>>(WiT, WsumT);
    // y_base = Xb @ WsumT^T  (bf16 out, vec epilogue); 64 mtiles x 32 coltiles
    gemm_mt<bf16, true><<<dim3(64 * 32), dim3(256), 0, stream>>>(
        Xb, E_DIM, WsumT, E_DIM, Yb, O_DIM, E_DIM);
    // expert-sorted padded copy of X (after base gemm: Xb/WsumT then dead)
    gather_rows<<<dim3(17408), dim3(128), 0, stream>>>(Xb, cnt, offp, tok, Xs);
    // slot partials: scale * sortedX @ Wi[g]  (ysp overlays Xb/WsumT)
    gemm_sparse<<<dim3(G_DIM * 64 * 32), dim3(256), 0, stream>>>(
        Xs, WiT, cnt, off, offp, scl, ysp);
    relu2_gather<<<dim3(N_TOK), dim3(256), 0, stream>>>(Yb, ysp, pos, off, Hh);
    // out = Hh @ dnT^T  (fp32 out); 64 mtiles x 8 coltiles
    gemm_mt<float, false><<<dim3(64 * 8), dim3(256), 0, stream>>>(
        Hh, O_DIM, dnT, O_DIM, out, E_DIM, O_DIM);
}